// Round 1
// baseline (1674.869 us; speedup 1.0000x reference)
//
#include <hip/hip_runtime.h>
#include <math.h>

#define F_FILT   40
#define K_GABOR  401
#define K_POOL   401
#define HOP      160
#define T_LEN    160000
#define B_BATCH  8
#define EPS_PCENF 1e-6f
#define EPS_INF   1e-5f

#define SEGS      4
#define SEGLEN    40000      // T_LEN / SEGS, multiple of TILE and HOP
#define THREADS   320        // 5 waves
#define RT        5
#define TILE      1600       // THREADS*RT, multiple of HOP
#define NTILES    25         // SEGLEN / TILE
#define NPOOL_SEG 250        // SEGLEN / HOP
#define N_PER_TILE 10        // TILE / HOP
#define HALO      400        // K_GABOR - 1
#define XS_LEN    (TILE + HALO)   // 2000
#define RING_LEN  (TILE + HALO)   // 2000
#define NWAVES    (THREADS / 64)  // 5

__global__ __launch_bounds__(THREADS) void leaf_main(
    const float* __restrict__ x,
    const float* __restrict__ eta_g,
    const float* __restrict__ sigma_g,
    const float* __restrict__ bw_g,
    const float* __restrict__ bias_g,
    const float* __restrict__ ema_g,
    const float* __restrict__ alpha_g,
    const float* __restrict__ delta_g,
    const float* __restrict__ root_g,
    float* __restrict__ out)
{
    __shared__ float  xs[XS_LEN];
    __shared__ float2 wcs[K_GABOR];
    __shared__ float  pk[K_POOL];
    __shared__ float  ring[RING_LEN];
    __shared__ float  pooled[NPOOL_SEG];
    __shared__ float  waveV[NWAVES];
    __shared__ float  cwArr[NWAVES];
    __shared__ float  carryLds;
    __shared__ float  p0Lds;

    const int blk  = blockIdx.x;
    const int s    = blk % SEGS;
    const int bf   = blk / SEGS;
    const int f    = bf % F_FILT;
    const int b    = bf / F_FILT;
    const int tid  = threadIdx.x;
    const int lane = tid & 63;
    const int wave = tid >> 6;

    const float eta   = eta_g[f];
    const float sigma = sigma_g[f];
    const float bw    = fminf(fmaxf(bw_g[f], 2.0f / (float)K_POOL), 0.5f);
    const float sw    = fminf(fmaxf(ema_g[f], 0.0f), 1.0f);
    const float a     = 1.0f - sw;
    const float alpha = fminf(alpha_g[f], 1.0f);
    const float inv_r = 1.0f / fmaxf(root_g[f], 1.0f);
    const float dlt   = delta_g[f];
    const float dpow  = powf(dlt, inv_r);

    // Fill gabor + pooling kernels in LDS
    {
        const float envc = 0.3989422804014327f / sigma;
        const float den  = bw * 0.5f * (float)(K_POOL - 1);
        for (int i = tid; i < K_GABOR; i += THREADS) {
            float t  = (float)(i - 200);
            float z  = t / sigma;
            float e  = envc * expf(-0.5f * z * z);
            float ph = eta * t;
            wcs[i] = make_float2(e * cosf(ph), e * sinf(ph));
            float tp = (float)(i - 201);   // arange(-201, 200)
            float d  = tp / den;
            pk[i] = expf(-0.5f * d * d);
        }
    }
    for (int i = tid; i < NPOOL_SEG; i += THREADS) pooled[i] = 0.0f;
    for (int i = tid; i < HALO; i += THREADS) ring[i] = 0.0f;
    if (tid == 0) carryLds = 0.0f;

    // powers of a for the scan:  A1 = a^RT
    const float A1  = a * a * a * a * a;
    const float A2  = A1 * A1, A4 = A2 * A2, A8 = A4 * A4;
    const float A16 = A8 * A8, A32 = A16 * A16, A64 = A32 * A32;
    const float ap1 = a, ap2 = a * a, ap3 = ap2 * a, ap4 = ap3 * a, ap5 = ap4 * a;
    // A1^lane via binary expansion (uniform-accurate)
    float Al = 1.0f;
    if (lane & 1)  Al *= A1;
    if (lane & 2)  Al *= A2;
    if (lane & 4)  Al *= A4;
    if (lane & 8)  Al *= A8;
    if (lane & 16) Al *= A16;
    if (lane & 32) Al *= A32;

    const float* xb = x + (size_t)b * T_LEN;
    const int t0 = s * SEGLEN;
    const int itStart = (s == 0) ? 0 : -1;   // warm-up tile for s>0

    for (int it = itStart; it < NTILES; ++it) {
        const int tileT0 = t0 + it * TILE;
        __syncthreads();   // protect xs + ring tail vs previous iteration
        // stage x tile (with left halo) into LDS
        for (int i = tid; i < XS_LEN; i += THREADS) {
            int gi = tileT0 - HALO + i;
            xs[i] = (gi >= 0) ? xb[gi] : 0.0f;
        }
        __syncthreads();

        // ---- Gabor conv + power ----
        const int r0 = tid * RT;
        float yc[RT], ys[RT];
#pragma unroll
        for (int r = 0; r < RT; ++r) { yc[r] = 0.0f; ys[r] = 0.0f; }
        const float* xsp = xs + r0;
#pragma unroll 4
        for (int k = 0; k < K_GABOR; ++k) {
            float2 w = wcs[k];
#pragma unroll
            for (int r = 0; r < RT; ++r) {
                float xv = xsp[k + r];
                yc[r] = fmaf(w.x, xv, yc[r]);
                ys[r] = fmaf(w.y, xv, ys[r]);
            }
        }
        float p[RT], u[RT];
        float uu = 0.0f;
#pragma unroll
        for (int r = 0; r < RT; ++r) {
            p[r] = yc[r] * yc[r] + ys[r] * ys[r];
            uu = fmaf(a, uu, sw * p[r]);
            u[r] = uu;
        }
        if (s == 0 && it == 0 && tid == 0) p0Lds = p[0];

        // ---- EMA: Kogge-Stone scan over thread carries (factor A1 = a^RT) ----
        float v = uu;
        {
            float tv;
            tv = __shfl_up(v, 1);  if (lane >= 1)  v = fmaf(A1,  tv, v);
            tv = __shfl_up(v, 2);  if (lane >= 2)  v = fmaf(A2,  tv, v);
            tv = __shfl_up(v, 4);  if (lane >= 4)  v = fmaf(A4,  tv, v);
            tv = __shfl_up(v, 8);  if (lane >= 8)  v = fmaf(A8,  tv, v);
            tv = __shfl_up(v, 16); if (lane >= 16) v = fmaf(A16, tv, v);
            tv = __shfl_up(v, 32); if (lane >= 32) v = fmaf(A32, tv, v);
        }
        if (lane == 63) waveV[wave] = v;
        __syncthreads();
        if (tid == 0) {
            float c = carryLds;
            if (s == 0 && it == 0) c = p0Lds;   // ema[0] = p[0] exact
#pragma unroll
            for (int w = 0; w < NWAVES; ++w) {
                cwArr[w] = c;                    // state before wave w
                c = fmaf(A64, c, waveV[w]);      // A^64 = a^320 per wave
            }
            carryLds = c;                        // state after tile
        }
        __syncthreads();
        float cin;
        {
            float cw = cwArr[wave];
            float ve = __shfl_up(v, 1);
            if (lane == 0) ve = 0.0f;
            cin = fmaf(Al, cw, ve);              // state before this thread
        }

        // ---- PCEN + write comp into ring ----
#pragma unroll
        for (int r = 0; r < RT; ++r) {
            float apr = (r == 0) ? ap1 : (r == 1) ? ap2 : (r == 2) ? ap3
                      : (r == 3) ? ap4 : ap5;
            float e    = fmaf(apr, cin, u[r]);            // ema value
            float denp = exp2f(alpha * log2f(EPS_PCENF + e));
            float q    = p[r] / denp + dlt;
            float comp = exp2f(inv_r * log2f(q)) - dpow;
            ring[HALO + r0 + r] = comp;
        }
        __syncthreads();

        // ---- pooling: 10 outputs per tile, 32 threads each ----
        if (it >= 0) {
            const int g   = tid >> 5;    // 0..9
            const int i32 = tid & 31;
            float part = 0.0f;
            for (int k = i32; k < K_POOL; k += 32)
                part = fmaf(pk[k], ring[g * HOP + k], part);
            part += __shfl_xor(part, 1, 32);
            part += __shfl_xor(part, 2, 32);
            part += __shfl_xor(part, 4, 32);
            part += __shfl_xor(part, 8, 32);
            part += __shfl_xor(part, 16, 32);
            if (i32 == 0) pooled[it * N_PER_TILE + g] += part;
        }
        __syncthreads();
        // slide ring tail (last HALO comps) to front
        for (int i = tid; i < HALO; i += THREADS) ring[i] = ring[TILE + i];
    }
    __syncthreads();

    const float bias = bias_g[f];
    for (int i = tid; i < NPOOL_SEG; i += THREADS) {
        out[(size_t)bf * 1000 + (size_t)s * NPOOL_SEG + i] = pooled[i] + bias;
    }
}

// ---- instance norm over the 1000 pooled frames, in place on d_out ----
__global__ __launch_bounds__(256) void leaf_norm(float* __restrict__ out)
{
    const int bf = blockIdx.x;
    float* p = out + (size_t)bf * 1000;
    __shared__ float buf[1000];
    __shared__ float red[4];
    const int tid = threadIdx.x;
    const int lane = tid & 63, wave = tid >> 6;

    float sum = 0.0f;
    for (int i = tid; i < 1000; i += 256) { float v = p[i]; buf[i] = v; sum += v; }
    for (int m = 1; m < 64; m <<= 1) sum += __shfl_xor(sum, m);
    if (lane == 0) red[wave] = sum;
    __syncthreads();
    const float mean = (red[0] + red[1] + red[2] + red[3]) * 0.001f;

    float vs = 0.0f;
    for (int i = tid; i < 1000; i += 256) { float d = buf[i] - mean; vs += d * d; }
    for (int m = 1; m < 64; m <<= 1) vs += __shfl_xor(vs, m);
    __syncthreads();
    if (lane == 0) red[wave] = vs;
    __syncthreads();
    const float var   = (red[0] + red[1] + red[2] + red[3]) * 0.001f;
    const float scale = rsqrtf(var + EPS_INF);
    for (int i = tid; i < 1000; i += 256) p[i] = (buf[i] - mean) * scale;
}

extern "C" void kernel_launch(void* const* d_in, const int* in_sizes, int n_in,
                              void* d_out, int out_size, void* d_ws, size_t ws_size,
                              hipStream_t stream)
{
    const float* x     = (const float*)d_in[0];
    const float* eta   = (const float*)d_in[1];
    const float* sigma = (const float*)d_in[2];
    const float* bw    = (const float*)d_in[3];
    const float* bias  = (const float*)d_in[4];
    const float* emaw  = (const float*)d_in[5];
    const float* alpha = (const float*)d_in[6];
    const float* delta = (const float*)d_in[7];
    const float* root  = (const float*)d_in[8];
    float* outp = (float*)d_out;

    hipLaunchKernelGGL(leaf_main, dim3(B_BATCH * F_FILT * SEGS), dim3(THREADS), 0, stream,
                       x, eta, sigma, bw, bias, emaw, alpha, delta, root, outp);
    hipLaunchKernelGGL(leaf_norm, dim3(B_BATCH * F_FILT), dim3(256), 0, stream, outp);
}

// Round 3
// 1159.609 us; speedup vs baseline: 1.4443x; 1.4443x over previous
//
#include <hip/hip_runtime.h>
#include <math.h>

#define F_FILT   40
#define K_GABOR  401
#define HOP      160
#define T_LEN    160000
#define B_BATCH  8
#define EPS_PCENF 1e-6f
#define EPS_INF   1e-5f

#define THREADS  320
#define NWAVES   5
#define RT       10
#define TILE     3200        // THREADS*RT
#define SEGS     5
#define SEGLEN   32000       // T_LEN/SEGS
#define NTILES   10          // SEGLEN/TILE
#define NPT      20          // pooled outputs per tile (TILE/HOP)
#define NPOOL_SEG 200
#define KP       208         // tap pairs, padded (401 taps -> 201 pairs -> 208)
#define HALOP    200         // halo pairs (400 samples)
#define TILEP    1600        // tile pairs
#define XEP      1824        // xE pairs incl. zero pad (max read 1810)
#define RINGP    1800        // comp ring pairs (halo+tile)

typedef _Float16 h2_t __attribute__((ext_vector_type(2)));

__device__ __forceinline__ float fdot2(h2_t a, h2_t b, float c) {
    return __builtin_amdgcn_fdot2(a, b, c, false);
}
__device__ __forceinline__ unsigned pk2(float a, float b) {
    return __builtin_bit_cast(unsigned, __builtin_amdgcn_cvt_pkrtz(a, b));
}
__device__ __forceinline__ h2_t bch(unsigned u) {
    return __builtin_bit_cast(h2_t, u);
}
__device__ __forceinline__ unsigned alignhi(unsigned hi, unsigned lo) {
    return __builtin_amdgcn_alignbit(hi, lo, 16);   // (lo>>16)|(hi<<16)
}

// ---------- setup: per-filter f16-packed gabor + pool kernels into d_ws ----------
__global__ __launch_bounds__(256) void leaf_weights(
    const float* __restrict__ eta_g, const float* __restrict__ sigma_g,
    const float* __restrict__ bw_g,
    uint2* __restrict__ wtab, unsigned* __restrict__ pktab)
{
    const int f = blockIdx.x;
    const int i = threadIdx.x;
    if (i >= KP) return;
    const float eta   = eta_g[f];
    const float sigma = sigma_g[f];
    const float bw    = fminf(fmaxf(bw_g[f], 2.0f / 401.0f), 0.5f);
    const float envc  = 0.3989422804014327f / sigma;
    const float den   = bw * 0.5f * 400.0f;

    float wc[2], ws[2], pp[2];
    for (int j = 0; j < 2; ++j) {
        int k = 2 * i + j;
        if (k < K_GABOR) {
            float t = (float)(k - 200);
            float z = t / sigma;
            float e = envc * expf(-0.5f * z * z);
            float ph = eta * t;
            wc[j] = e * cosf(ph);
            ws[j] = e * sinf(ph);
            float tp = (float)(k - 201);
            float d = tp / den;
            pp[j] = expf(-0.5f * d * d);
        } else { wc[j] = 0.f; ws[j] = 0.f; pp[j] = 0.f; }
    }
    wtab[f * KP + i]  = make_uint2(pk2(wc[0], wc[1]), pk2(ws[0], ws[1]));
    pktab[f * KP + i] = pk2(pp[0], pp[1]);
}

// ---------- main fused kernel ----------
__global__ __launch_bounds__(THREADS) void leaf_main(
    const float* __restrict__ x,
    const float* __restrict__ bias_g,
    const float* __restrict__ ema_g,
    const float* __restrict__ alpha_g,
    const float* __restrict__ delta_g,
    const float* __restrict__ root_g,
    const uint2* __restrict__ wtab,
    const unsigned* __restrict__ pktab,
    float* __restrict__ out)
{
    __shared__ unsigned xEl[XEP];     // x as f16 pairs (even phase)
    __shared__ unsigned ringl[RINGP]; // comp as f16 pairs
    __shared__ unsigned pkpl[KP];     // pool kernel f16 pairs
    __shared__ float pooled[NPOOL_SEG];
    __shared__ float waveV[NWAVES], cwArr[NWAVES];
    __shared__ float carryLds, p0Lds;

    const int blk  = blockIdx.x;
    const int s    = blk % SEGS;
    const int bf   = blk / SEGS;
    const int f    = bf % F_FILT;
    const int b    = bf / F_FILT;
    const int tid  = threadIdx.x;
    const int lane = tid & 63;
    const int wave = tid >> 6;

    const float sw    = fminf(fmaxf(ema_g[f], 0.0f), 1.0f);
    const float a     = 1.0f - sw;
    const float alpha = fminf(alpha_g[f], 1.0f);
    const float inv_r = 1.0f / fmaxf(root_g[f], 1.0f);
    const float dlt   = delta_g[f];
    const float dpow  = powf(dlt, inv_r);
    const uint2* __restrict__ wt = wtab + (size_t)f * KP;

    // init LDS
    for (int i = tid; i < XEP;   i += THREADS) xEl[i] = 0u;
    for (int i = tid; i < RINGP; i += THREADS) ringl[i] = 0u;
    for (int i = tid; i < NPOOL_SEG; i += THREADS) pooled[i] = 0.f;
    if (tid < KP) pkpl[tid] = pktab[f * KP + tid];
    if (tid == 0) carryLds = 0.f;

    // scan factors: A1 = a^RT
    const float a2 = a * a, a4 = a2 * a2, a8 = a4 * a4;
    const float A1  = a8 * a2;          // a^10
    const float A2  = A1 * A1, A4 = A2 * A2, A8 = A4 * A4;
    const float A16 = A8 * A8, A32 = A16 * A16, A64 = A32 * A32;
    float Al = 1.0f;
    if (lane & 1)  Al *= A1;
    if (lane & 2)  Al *= A2;
    if (lane & 4)  Al *= A4;
    if (lane & 8)  Al *= A8;
    if (lane & 16) Al *= A16;
    if (lane & 32) Al *= A32;

    const float* xb = x + (size_t)b * T_LEN;
    const int t0 = s * SEGLEN;
    const int itStart = (s == 0) ? 0 : -1;
    const unsigned P0 = 5u * (unsigned)tid;   // pair base = (tid*RT)/2

    for (int it = itStart; it < NTILES; ++it) {
        const int tileT0 = t0 + it * TILE;
        __syncthreads();
        // slide previous tails (x halo + comp halo), stage new tile
        const bool doSlide = (it != itStart);
        unsigned tx = 0u, tr = 0u;
        if (doSlide && tid < HALOP) { tx = xEl[TILEP + tid]; tr = ringl[TILEP + tid]; }
        float2 sv[5];
        const float2* src = (const float2*)(xb + tileT0);
#pragma unroll
        for (int t = 0; t < 5; ++t) sv[t] = src[tid + 320 * t];
        __syncthreads();
        if (doSlide && tid < HALOP) { xEl[tid] = tx; ringl[tid] = tr; }
#pragma unroll
        for (int t = 0; t < 5; ++t) xEl[HALOP + tid + 320 * t] = pk2(sv[t].x, sv[t].y);
        __syncthreads();

        // ---- Gabor conv via dot2: RT outputs, 8-slot rotating pair window ----
        float ac[RT], as_[RT];
#pragma unroll
        for (int r = 0; r < RT; ++r) { ac[r] = 0.f; as_[r] = 0.f; }
        unsigned E[8], Ow[8];
#pragma unroll
        for (int j = 0; j < 8; ++j) E[j] = xEl[P0 + j];
#pragma unroll
        for (int j = 0; j < 6; ++j) Ow[j] = alignhi(E[j + 1], E[j]);

        for (int kp8 = 0; kp8 < KP / 8; ++kp8) {
#pragma unroll
            for (int u = 0; u < 8; ++u) {
                const int kp = kp8 * 8 + u;
                const uint2 wv = wt[kp];
                const h2_t wc2 = bch(wv.x), ws2 = bch(wv.y);
#pragma unroll
                for (int j = 0; j < 5; ++j) {
                    const h2_t xe = bch(E[(u + j) & 7]);
                    ac[2 * j]      = fdot2(xe, wc2, ac[2 * j]);
                    as_[2 * j]     = fdot2(xe, ws2, as_[2 * j]);
                    const h2_t xo = bch(Ow[(u + j) & 7]);
                    ac[2 * j + 1]  = fdot2(xo, wc2, ac[2 * j + 1]);
                    as_[2 * j + 1] = fdot2(xo, ws2, as_[2 * j + 1]);
                }
                E[u] = xEl[P0 + kp + 8];                       // pos kp+8
                Ow[(u + 6) & 7] = alignhi(E[(u + 7) & 7], E[(u + 6) & 7]); // pos kp+6
            }
        }

        // ---- power + thread-local EMA ----
        float p[RT], up[RT];
        float uu = 0.f;
#pragma unroll
        for (int r = 0; r < RT; ++r) {
            p[r] = fmaf(ac[r], ac[r], as_[r] * as_[r]);
            uu = fmaf(a, uu, sw * p[r]);
            up[r] = uu;
        }
        if (s == 0 && it == 0 && tid == 0) p0Lds = p[0];

        // ---- EMA Kogge-Stone scan over threads ----
        float v = uu;
        {
            float tv;
            tv = __shfl_up(v, 1);  if (lane >= 1)  v = fmaf(A1,  tv, v);
            tv = __shfl_up(v, 2);  if (lane >= 2)  v = fmaf(A2,  tv, v);
            tv = __shfl_up(v, 4);  if (lane >= 4)  v = fmaf(A4,  tv, v);
            tv = __shfl_up(v, 8);  if (lane >= 8)  v = fmaf(A8,  tv, v);
            tv = __shfl_up(v, 16); if (lane >= 16) v = fmaf(A16, tv, v);
            tv = __shfl_up(v, 32); if (lane >= 32) v = fmaf(A32, tv, v);
        }
        if (lane == 63) waveV[wave] = v;
        __syncthreads();
        if (tid == 0) {
            float c = (s == 0 && it == 0) ? p0Lds : carryLds;
#pragma unroll
            for (int w = 0; w < NWAVES; ++w) { cwArr[w] = c; c = fmaf(A64, c, waveV[w]); }
            carryLds = c;
        }
        __syncthreads();
        float cin;
        {
            const float cw = cwArr[wave];
            float ve = __shfl_up(v, 1);
            if (lane == 0) ve = 0.f;
            cin = fmaf(Al, cw, ve);
        }

        // ---- PCEN + f16 ring writes ----
        float apr = a;
#pragma unroll
        for (int j = 0; j < 5; ++j) {
            const float e0 = fmaf(apr, cin, up[2 * j]);     apr *= a;
            const float e1 = fmaf(apr, cin, up[2 * j + 1]); apr *= a;
            const float q0 = fmaf(p[2 * j],     exp2f(-alpha * log2f(EPS_PCENF + e0)), dlt);
            const float q1 = fmaf(p[2 * j + 1], exp2f(-alpha * log2f(EPS_PCENF + e1)), dlt);
            const float c0 = exp2f(inv_r * log2f(q0)) - dpow;
            const float c1 = exp2f(inv_r * log2f(q1)) - dpow;
            ringl[HALOP + P0 + j] = pk2(c0, c1);
        }
        __syncthreads();

        // ---- pooling via dot2: 20 outputs x 16 lanes ----
        if (it >= 0) {
            const int o = tid >> 4, l = tid & 15;
            float part = 0.f;
#pragma unroll
            for (int t = 0; t < 13; ++t) {
                const int kpp = l + 16 * t;   // 0..207, pkpl zero-padded
                part = fdot2(bch(ringl[o * 80 + kpp]), bch(pkpl[kpp]), part);
            }
            part += __shfl_xor(part, 1, 16);
            part += __shfl_xor(part, 2, 16);
            part += __shfl_xor(part, 4, 16);
            part += __shfl_xor(part, 8, 16);
            if (l == 0) pooled[it * NPT + o] += part;
        }
    }
    __syncthreads();

    const float bias = bias_g[f];
    for (int i = tid; i < NPOOL_SEG; i += THREADS)
        out[(size_t)bf * 1000 + (size_t)s * NPOOL_SEG + i] = pooled[i] + bias;
}

// ---------- instance norm over 1000 frames, in place ----------
__global__ __launch_bounds__(256) void leaf_norm(float* __restrict__ out)
{
    const int bf = blockIdx.x;
    float* p = out + (size_t)bf * 1000;
    __shared__ float buf[1000];
    __shared__ float red[4];
    const int tid = threadIdx.x;
    const int lane = tid & 63, wave = tid >> 6;

    float sum = 0.0f;
    for (int i = tid; i < 1000; i += 256) { float v = p[i]; buf[i] = v; sum += v; }
    for (int m = 1; m < 64; m <<= 1) sum += __shfl_xor(sum, m);
    if (lane == 0) red[wave] = sum;
    __syncthreads();
    const float mean = (red[0] + red[1] + red[2] + red[3]) * 0.001f;

    float vs = 0.0f;
    for (int i = tid; i < 1000; i += 256) { float d = buf[i] - mean; vs += d * d; }
    for (int m = 1; m < 64; m <<= 1) vs += __shfl_xor(vs, m);
    __syncthreads();
    if (lane == 0) red[wave] = vs;
    __syncthreads();
    const float var   = (red[0] + red[1] + red[2] + red[3]) * 0.001f;
    const float scale = rsqrtf(var + EPS_INF);
    for (int i = tid; i < 1000; i += 256) p[i] = (buf[i] - mean) * scale;
}

extern "C" void kernel_launch(void* const* d_in, const int* in_sizes, int n_in,
                              void* d_out, int out_size, void* d_ws, size_t ws_size,
                              hipStream_t stream)
{
    const float* x     = (const float*)d_in[0];
    const float* eta   = (const float*)d_in[1];
    const float* sigma = (const float*)d_in[2];
    const float* bw    = (const float*)d_in[3];
    const float* bias  = (const float*)d_in[4];
    const float* emaw  = (const float*)d_in[5];
    const float* alpha = (const float*)d_in[6];
    const float* delta = (const float*)d_in[7];
    const float* root  = (const float*)d_in[8];
    float* outp = (float*)d_out;

    uint2*    wtab  = (uint2*)d_ws;                                   // 40*208*8 B
    unsigned* pktab = (unsigned*)((char*)d_ws + (size_t)F_FILT * KP * sizeof(uint2));

    hipLaunchKernelGGL(leaf_weights, dim3(F_FILT), dim3(256), 0, stream,
                       eta, sigma, bw, wtab, pktab);
    hipLaunchKernelGGL(leaf_main, dim3(B_BATCH * F_FILT * SEGS), dim3(THREADS), 0, stream,
                       x, bias, emaw, alpha, delta, root, wtab, pktab, outp);
    hipLaunchKernelGGL(leaf_norm, dim3(B_BATCH * F_FILT), dim3(256), 0, stream, outp);
}

// Round 4
// 920.378 us; speedup vs baseline: 1.8198x; 1.2599x over previous
//
#include <hip/hip_runtime.h>
#include <math.h>

#define F_FILT   40
#define K_GABOR  401
#define HOP      160
#define T_LEN    160000
#define B_BATCH  8
#define EPS_PCENF 1e-6f
#define EPS_INF   1e-5f

#define THREADS  320
#define NWAVES   5
#define RT       10
#define TILE     3200        // THREADS*RT
#define SEGS     5
#define SEGLEN   32000       // T_LEN/SEGS
#define NTILES   10          // SEGLEN/TILE
#define NPT      20          // pooled outputs per tile (TILE/HOP)
#define NPOOL_SEG 200
#define KP       208         // tap pairs, padded (401 taps -> 201 pairs -> 208)
#define KPW      224         // weight table pairs (prefetch overrun pad)
#define HALOP    200         // halo pairs (400 samples)
#define TILEP    1600        // tile pairs
#define XEP      1824        // xE pairs incl. zero pad (max read 1810)
#define RINGP    1800        // comp ring pairs (halo+tile)

typedef _Float16 h2_t __attribute__((ext_vector_type(2)));

__device__ __forceinline__ float fdot2(h2_t a, h2_t b, float c) {
    return __builtin_amdgcn_fdot2(a, b, c, false);
}
__device__ __forceinline__ unsigned pk2(float a, float b) {
    return __builtin_bit_cast(unsigned, __builtin_amdgcn_cvt_pkrtz(a, b));
}
__device__ __forceinline__ h2_t bch(unsigned u) {
    return __builtin_bit_cast(h2_t, u);
}
__device__ __forceinline__ unsigned alignhi(unsigned hi, unsigned lo) {
    return __builtin_amdgcn_alignbit(hi, lo, 16);   // (lo>>16)|(hi<<16)
}

// ---------- setup: per-filter f16-packed gabor + pool kernels into d_ws ----------
__global__ __launch_bounds__(256) void leaf_weights(
    const float* __restrict__ eta_g, const float* __restrict__ sigma_g,
    const float* __restrict__ bw_g,
    uint2* __restrict__ wtab, unsigned* __restrict__ pktab)
{
    const int f = blockIdx.x;
    const int i = threadIdx.x;
    if (i >= KPW) return;
    const float eta   = eta_g[f];
    const float sigma = sigma_g[f];
    const float bw    = fminf(fmaxf(bw_g[f], 2.0f / 401.0f), 0.5f);
    const float envc  = 0.3989422804014327f / sigma;
    const float den   = bw * 0.5f * 400.0f;

    float wc[2], ws[2], pp[2];
    for (int j = 0; j < 2; ++j) {
        int k = 2 * i + j;
        if (k < K_GABOR) {
            float t = (float)(k - 200);
            float z = t / sigma;
            float e = envc * expf(-0.5f * z * z);
            float ph = eta * t;
            wc[j] = e * cosf(ph);
            ws[j] = e * sinf(ph);
            float tp = (float)(k - 201);
            float d = tp / den;
            pp[j] = expf(-0.5f * d * d);
        } else { wc[j] = 0.f; ws[j] = 0.f; pp[j] = 0.f; }
    }
    wtab[f * KPW + i] = make_uint2(pk2(wc[0], wc[1]), pk2(ws[0], ws[1]));
    if (i < KP) pktab[f * KP + i] = pk2(pp[0], pp[1]);
}

// ---------- main fused kernel ----------
__global__ __launch_bounds__(THREADS) void leaf_main(
    const float* __restrict__ x,
    const float* __restrict__ sigma_g,
    const float* __restrict__ bias_g,
    const float* __restrict__ ema_g,
    const float* __restrict__ alpha_g,
    const float* __restrict__ delta_g,
    const float* __restrict__ root_g,
    const uint2* __restrict__ wtab,
    const unsigned* __restrict__ pktab,
    float* __restrict__ out)
{
    __shared__ unsigned xEl[XEP];     // x as f16 pairs (even phase)
    __shared__ unsigned ringl[RINGP]; // comp as f16 pairs
    __shared__ unsigned pkpl[KP];     // pool kernel f16 pairs
    __shared__ float pooled[NPOOL_SEG];
    __shared__ float waveV[NWAVES], cwArr[NWAVES];
    __shared__ float carryLds, p0Lds;

    const int blk  = blockIdx.x;
    const int s    = blk / (B_BATCH * F_FILT);   // bf fastest: spreads heavy filters
    const int bf   = blk % (B_BATCH * F_FILT);
    const int f    = bf % F_FILT;
    const int b    = bf / F_FILT;
    const int tid  = threadIdx.x;
    const int lane = tid & 63;
    const int wave = tid >> 6;

    const float sw    = fminf(fmaxf(ema_g[f], 0.0f), 1.0f);
    const float a     = 1.0f - sw;
    const float alpha = fminf(alpha_g[f], 1.0f);
    const float inv_r = 1.0f / fmaxf(root_g[f], 1.0f);
    const float dlt   = delta_g[f];
    const float dpow  = powf(dlt, inv_r);

    // truncated support: taps |k-200| <= R = 4.5*sigma
    const float sigma = sigma_g[f];
    const int R   = min(200, (int)ceilf(4.5f * sigma));
    const int S8  = ((200 - R) >> 1) & ~7;        // 8-aligned start pair
    const int hiP = (200 + R) >> 1;
    int ni = ((hiP - S8) >> 3) + 1;
    ni = min(ni, (KP - S8) >> 3);
    const uint2* __restrict__ wtp = wtab + (size_t)f * KPW + S8;

    // init LDS
    for (int i = tid; i < XEP;   i += THREADS) xEl[i] = 0u;
    for (int i = tid; i < RINGP; i += THREADS) ringl[i] = 0u;
    for (int i = tid; i < NPOOL_SEG; i += THREADS) pooled[i] = 0.f;
    if (tid < KP) pkpl[tid] = pktab[f * KP + tid];
    if (tid == 0) carryLds = 0.f;

    // scan factors: A1 = a^RT
    const float a2 = a * a, a4 = a2 * a2, a8 = a4 * a4;
    const float A1  = a8 * a2;          // a^10
    const float A2  = A1 * A1, A4 = A2 * A2, A8 = A4 * A4;
    const float A16 = A8 * A8, A32 = A16 * A16, A64 = A32 * A32;
    float Al = 1.0f;
    if (lane & 1)  Al *= A1;
    if (lane & 2)  Al *= A2;
    if (lane & 4)  Al *= A4;
    if (lane & 8)  Al *= A8;
    if (lane & 16) Al *= A16;
    if (lane & 32) Al *= A32;

    const float* xb = x + (size_t)b * T_LEN;
    const int t0 = s * SEGLEN;
    const int itStart = (s == 0) ? 0 : -1;
    const unsigned P0 = 5u * (unsigned)tid;   // pair base = (tid*RT)/2
    const unsigned PS = P0 + (unsigned)S8;

    for (int it = itStart; it < NTILES; ++it) {
        const int tileT0 = t0 + it * TILE;
        __syncthreads();
        // slide previous tails (x halo + comp halo), stage new tile
        const bool doSlide = (it != itStart);
        unsigned tx = 0u, tr = 0u;
        if (doSlide && tid < HALOP) { tx = xEl[TILEP + tid]; tr = ringl[TILEP + tid]; }
        float2 sv[5];
        const float2* src = (const float2*)(xb + tileT0);
#pragma unroll
        for (int t = 0; t < 5; ++t) sv[t] = src[tid + 320 * t];
        __syncthreads();
        if (doSlide && tid < HALOP) { xEl[tid] = tx; ringl[tid] = tr; }
#pragma unroll
        for (int t = 0; t < 5; ++t) xEl[HALOP + tid + 320 * t] = pk2(sv[t].x, sv[t].y);
        __syncthreads();

        // ---- Gabor conv via dot2: RT outputs, 8-slot rotating pair window ----
        float ac[RT], as_[RT];
#pragma unroll
        for (int r = 0; r < RT; ++r) { ac[r] = 0.f; as_[r] = 0.f; }
        unsigned E[8], Ow[8];
#pragma unroll
        for (int j = 0; j < 8; ++j) E[j] = xEl[PS + j];
#pragma unroll
        for (int j = 0; j < 6; ++j) Ow[j] = alignhi(E[j + 1], E[j]);
        uint2 wbuf[8];
#pragma unroll
        for (int u = 0; u < 8; ++u) wbuf[u] = wtp[u];

        for (int i8 = 0; i8 < ni; ++i8) {
            uint2 wnext[8];
            const uint2* wn = wtp + (i8 + 1) * 8;   // table padded to KPW
#pragma unroll
            for (int u = 0; u < 8; ++u) wnext[u] = wn[u];
#pragma unroll
            for (int u = 0; u < 8; ++u) {
                const h2_t wc2 = bch(wbuf[u].x), ws2 = bch(wbuf[u].y);
#pragma unroll
                for (int j = 0; j < 5; ++j) {
                    const h2_t xe = bch(E[(u + j) & 7]);
                    ac[2 * j]      = fdot2(xe, wc2, ac[2 * j]);
                    as_[2 * j]     = fdot2(xe, ws2, as_[2 * j]);
                    const h2_t xo = bch(Ow[(u + j) & 7]);
                    ac[2 * j + 1]  = fdot2(xo, wc2, ac[2 * j + 1]);
                    as_[2 * j + 1] = fdot2(xo, ws2, as_[2 * j + 1]);
                }
                E[u] = xEl[PS + i8 * 8 + u + 8];
                Ow[(u + 6) & 7] = alignhi(E[(u + 7) & 7], E[(u + 6) & 7]);
            }
#pragma unroll
            for (int u = 0; u < 8; ++u) wbuf[u] = wnext[u];
        }

        // ---- power + thread-local EMA ----
        float p[RT], up[RT];
        float uu = 0.f;
#pragma unroll
        for (int r = 0; r < RT; ++r) {
            p[r] = fmaf(ac[r], ac[r], as_[r] * as_[r]);
            uu = fmaf(a, uu, sw * p[r]);
            up[r] = uu;
        }
        if (s == 0 && it == 0 && tid == 0) p0Lds = p[0];

        // ---- EMA Kogge-Stone scan over threads ----
        float v = uu;
        {
            float tv;
            tv = __shfl_up(v, 1);  if (lane >= 1)  v = fmaf(A1,  tv, v);
            tv = __shfl_up(v, 2);  if (lane >= 2)  v = fmaf(A2,  tv, v);
            tv = __shfl_up(v, 4);  if (lane >= 4)  v = fmaf(A4,  tv, v);
            tv = __shfl_up(v, 8);  if (lane >= 8)  v = fmaf(A8,  tv, v);
            tv = __shfl_up(v, 16); if (lane >= 16) v = fmaf(A16, tv, v);
            tv = __shfl_up(v, 32); if (lane >= 32) v = fmaf(A32, tv, v);
        }
        if (lane == 63) waveV[wave] = v;
        __syncthreads();
        if (tid == 0) {
            float c = (s == 0 && it == 0) ? p0Lds : carryLds;
#pragma unroll
            for (int w = 0; w < NWAVES; ++w) { cwArr[w] = c; c = fmaf(A64, c, waveV[w]); }
            carryLds = c;
        }
        __syncthreads();
        float cin;
        {
            const float cw = cwArr[wave];
            float ve = __shfl_up(v, 1);
            if (lane == 0) ve = 0.f;
            cin = fmaf(Al, cw, ve);
        }

        // ---- PCEN + f16 ring writes ----
        float apr = a;
#pragma unroll
        for (int j = 0; j < 5; ++j) {
            const float e0 = fmaf(apr, cin, up[2 * j]);     apr *= a;
            const float e1 = fmaf(apr, cin, up[2 * j + 1]); apr *= a;
            const float q0 = fmaf(p[2 * j],     exp2f(-alpha * log2f(EPS_PCENF + e0)), dlt);
            const float q1 = fmaf(p[2 * j + 1], exp2f(-alpha * log2f(EPS_PCENF + e1)), dlt);
            const float c0 = exp2f(inv_r * log2f(q0)) - dpow;
            const float c1 = exp2f(inv_r * log2f(q1)) - dpow;
            ringl[HALOP + P0 + j] = pk2(c0, c1);
        }
        __syncthreads();

        // ---- pooling via dot2: 20 outputs x 16 lanes ----
        if (it >= 0) {
            const int o = tid >> 4, l = tid & 15;
            float part = 0.f;
#pragma unroll
            for (int t = 0; t < 13; ++t) {
                const int kpp = l + 16 * t;   // 0..207, pkpl zero-padded
                part = fdot2(bch(ringl[o * 80 + kpp]), bch(pkpl[kpp]), part);
            }
            part += __shfl_xor(part, 1, 16);
            part += __shfl_xor(part, 2, 16);
            part += __shfl_xor(part, 4, 16);
            part += __shfl_xor(part, 8, 16);
            if (l == 0) pooled[it * NPT + o] += part;
        }
    }
    __syncthreads();

    const float bias = bias_g[f];
    for (int i = tid; i < NPOOL_SEG; i += THREADS)
        out[(size_t)bf * 1000 + (size_t)s * NPOOL_SEG + i] = pooled[i] + bias;
}

// ---------- instance norm over 1000 frames, in place ----------
__global__ __launch_bounds__(256) void leaf_norm(float* __restrict__ out)
{
    const int bf = blockIdx.x;
    float* p = out + (size_t)bf * 1000;
    __shared__ float buf[1000];
    __shared__ float red[4];
    const int tid = threadIdx.x;
    const int lane = tid & 63, wave = tid >> 6;

    float sum = 0.0f;
    for (int i = tid; i < 1000; i += 256) { float v = p[i]; buf[i] = v; sum += v; }
    for (int m = 1; m < 64; m <<= 1) sum += __shfl_xor(sum, m);
    if (lane == 0) red[wave] = sum;
    __syncthreads();
    const float mean = (red[0] + red[1] + red[2] + red[3]) * 0.001f;

    float vs = 0.0f;
    for (int i = tid; i < 1000; i += 256) { float d = buf[i] - mean; vs += d * d; }
    for (int m = 1; m < 64; m <<= 1) vs += __shfl_xor(vs, m);
    __syncthreads();
    if (lane == 0) red[wave] = vs;
    __syncthreads();
    const float var   = (red[0] + red[1] + red[2] + red[3]) * 0.001f;
    const float scale = rsqrtf(var + EPS_INF);
    for (int i = tid; i < 1000; i += 256) p[i] = (buf[i] - mean) * scale;
}

extern "C" void kernel_launch(void* const* d_in, const int* in_sizes, int n_in,
                              void* d_out, int out_size, void* d_ws, size_t ws_size,
                              hipStream_t stream)
{
    const float* x     = (const float*)d_in[0];
    const float* eta   = (const float*)d_in[1];
    const float* sigma = (const float*)d_in[2];
    const float* bw    = (const float*)d_in[3];
    const float* bias  = (const float*)d_in[4];
    const float* emaw  = (const float*)d_in[5];
    const float* alpha = (const float*)d_in[6];
    const float* delta = (const float*)d_in[7];
    const float* root  = (const float*)d_in[8];
    float* outp = (float*)d_out;

    uint2*    wtab  = (uint2*)d_ws;                                   // 40*224*8 B
    unsigned* pktab = (unsigned*)((char*)d_ws + (size_t)F_FILT * KPW * sizeof(uint2));

    hipLaunchKernelGGL(leaf_weights, dim3(F_FILT), dim3(256), 0, stream,
                       eta, sigma, bw, wtab, pktab);
    hipLaunchKernelGGL(leaf_main, dim3(B_BATCH * F_FILT * SEGS), dim3(THREADS), 0, stream,
                       x, sigma, bias, emaw, alpha, delta, root, wtab, pktab, outp);
    hipLaunchKernelGGL(leaf_norm, dim3(B_BATCH * F_FILT), dim3(256), 0, stream, outp);
}

// Round 5
// 885.188 us; speedup vs baseline: 1.8921x; 1.0398x over previous
//
#include <hip/hip_runtime.h>
#include <math.h>

#define F_FILT   40
#define K_GABOR  401
#define HOP      160
#define T_LEN    160000
#define B_BATCH  8
#define EPS_PCENF 1e-6f
#define EPS_INF   1e-5f

#define THREADS  320
#define NWAVES   5
#define RT       10
#define TILE     3200        // THREADS*RT
#define TPC      5           // payload tiles per chunk/block
#define CHUNKS   10          // T_LEN / (TILE*TPC)
#define NPT      20          // pooled outputs per tile
#define NPOOL_BLK 100        // TPC*NPT
#define KP       208         // tap pairs (401 taps -> 201 pairs -> 208 padded)
#define KPW      224         // weight table stride (pad)
#define HALOP    200         // halo pairs (400 samples)
#define TILEP    1600        // tile pairs
#define XEP      1824        // x pairs incl. pad (max read 1810)
#define RINGP    1800        // comp ring pairs (halo+tile)
#define WLS_MAX  224         // max weight pairs staged per block

typedef _Float16 h2_t __attribute__((ext_vector_type(2)));

__device__ __forceinline__ float fdot2(h2_t a, h2_t b, float c) {
    return __builtin_amdgcn_fdot2(a, b, c, false);
}
__device__ __forceinline__ unsigned pk2(float a, float b) {
    return __builtin_bit_cast(unsigned, __builtin_amdgcn_cvt_pkrtz(a, b));
}
__device__ __forceinline__ h2_t bch(unsigned u) {
    return __builtin_bit_cast(h2_t, u);
}
__device__ __forceinline__ unsigned alignhi(unsigned hi, unsigned lo) {
    return __builtin_amdgcn_alignbit(hi, lo, 16);   // (lo>>16)|(hi<<16)
}

// ---------- setup: per-filter f16-packed gabor + pool kernels into d_ws ----------
__global__ __launch_bounds__(256) void leaf_weights(
    const float* __restrict__ eta_g, const float* __restrict__ sigma_g,
    const float* __restrict__ bw_g,
    uint2* __restrict__ wtab, unsigned* __restrict__ pktab)
{
    const int f = blockIdx.x;
    const int i = threadIdx.x;
    if (i >= KPW) return;
    const float eta   = eta_g[f];
    const float sigma = sigma_g[f];
    const float bw    = fminf(fmaxf(bw_g[f], 2.0f / 401.0f), 0.5f);
    const float envc  = 0.3989422804014327f / sigma;
    const float den   = bw * 0.5f * 400.0f;

    float wc[2], ws[2], pp[2];
    for (int j = 0; j < 2; ++j) {
        int k = 2 * i + j;
        if (k < K_GABOR) {
            float t = (float)(k - 200);
            float z = t / sigma;
            float e = envc * expf(-0.5f * z * z);
            float ph = eta * t;
            wc[j] = e * cosf(ph);
            ws[j] = e * sinf(ph);
            float tp = (float)(k - 201);
            float d = tp / den;
            pp[j] = expf(-0.5f * d * d);
        } else { wc[j] = 0.f; ws[j] = 0.f; pp[j] = 0.f; }
    }
    wtab[f * KPW + i] = make_uint2(pk2(wc[0], wc[1]), pk2(ws[0], ws[1]));
    if (i < KP) pktab[f * KP + i] = pk2(pp[0], pp[1]);
}

// ---------- main fused kernel: one block = (b, f, chunk of 5 tiles) ----------
__global__ __launch_bounds__(THREADS) void leaf_main(
    const float* __restrict__ x,
    const float* __restrict__ sigma_g,
    const float* __restrict__ bias_g,
    const float* __restrict__ ema_g,
    const float* __restrict__ alpha_g,
    const float* __restrict__ delta_g,
    const float* __restrict__ root_g,
    const uint2* __restrict__ wtab,
    const unsigned* __restrict__ pktab,
    float* __restrict__ out)
{
    __shared__ unsigned xEl[XEP];      // x as f16 pairs
    __shared__ unsigned ringl[RINGP];  // comp as f16 pairs
    __shared__ unsigned pkpl[KP];      // pool kernel f16 pairs
    __shared__ uint2    wls[WLS_MAX];  // gabor weights (truncated span)
    __shared__ float pooled[NPOOL_BLK];
    __shared__ float waveV[NWAVES], cwArr[NWAVES];
    __shared__ float carryLds, p0Lds;

    const int blk   = blockIdx.x;
    const int f     = blk % F_FILT;               // f fastest: mixes heavy/light
    const int b     = (blk / F_FILT) % B_BATCH;
    const int chunk = blk / (F_FILT * B_BATCH);
    const int bf    = b * F_FILT + f;
    const int tid  = threadIdx.x;
    const int lane = tid & 63;
    const int wave = tid >> 6;

    const float sw    = fminf(fmaxf(ema_g[f], 0.0f), 1.0f);
    const float a     = 1.0f - sw;
    const float alpha = fminf(alpha_g[f], 1.0f);
    const float inv_r = 1.0f / fmaxf(root_g[f], 1.0f);
    const float dlt   = delta_g[f];
    const float dpow  = powf(dlt, inv_r);

    // truncated support: taps |k-200| <= R = 4.5*sigma
    const float sigma = sigma_g[f];
    const int R   = min(200, (int)ceilf(4.5f * sigma));
    const int S8  = ((200 - R) >> 1) & ~7;        // 8-aligned start pair
    const int hiP = (200 + R) >> 1;
    int ni = ((hiP - S8) >> 3) + 1;
    ni = min(ni, (KP - S8) >> 3);

    // init LDS
    for (int i = tid; i < XEP;   i += THREADS) xEl[i] = 0u;
    for (int i = tid; i < RINGP; i += THREADS) ringl[i] = 0u;
    for (int i = tid; i < NPOOL_BLK; i += THREADS) pooled[i] = 0.f;
    if (tid < KP) pkpl[tid] = pktab[f * KP + tid];
    {
        const uint2* __restrict__ wtp = wtab + (size_t)f * KPW + S8;
        for (int i = tid; i < ni * 8; i += THREADS) wls[i] = wtp[i];
    }
    if (tid == 0) carryLds = 0.f;

    // scan factors: A1 = a^RT
    const float a2 = a * a, a4 = a2 * a2, a8 = a4 * a4;
    const float A1  = a8 * a2;          // a^10
    const float A2  = A1 * A1, A4 = A2 * A2, A8 = A4 * A4;
    const float A16 = A8 * A8, A32 = A16 * A16, A64 = A32 * A32;
    float Al = 1.0f;
    if (lane & 1)  Al *= A1;
    if (lane & 2)  Al *= A2;
    if (lane & 4)  Al *= A4;
    if (lane & 8)  Al *= A8;
    if (lane & 16) Al *= A16;
    if (lane & 32) Al *= A32;

    const float* xb = x + (size_t)b * T_LEN;
    const int tile0 = chunk * TPC;
    const int itStart = (chunk == 0) ? 0 : -1;    // warm-up tile for chunk>0
    const unsigned P0 = 5u * (unsigned)tid;       // pair base = (tid*RT)/2
    const unsigned PS = P0 + (unsigned)S8;

    for (int it = itStart; it < TPC; ++it) {
        const int tileT0 = (tile0 + it) * TILE;
        __syncthreads();
        // slide previous tails (x halo + comp halo), stage new tile
        const bool doSlide = (it != itStart);
        unsigned tx = 0u, tr = 0u;
        if (doSlide && tid < HALOP) { tx = xEl[TILEP + tid]; tr = ringl[TILEP + tid]; }
        float2 sv[5];
        const float2* src = (const float2*)(xb + tileT0);
#pragma unroll
        for (int t = 0; t < 5; ++t) sv[t] = src[tid + 320 * t];
        __syncthreads();
        if (doSlide && tid < HALOP) { xEl[tid] = tx; ringl[tid] = tr; }
#pragma unroll
        for (int t = 0; t < 5; ++t) xEl[HALOP + tid + 320 * t] = pk2(sv[t].x, sv[t].y);
        __syncthreads();

        // ---- Gabor conv via dot2: RT outputs, 8-slot rotating pair window ----
        float ac[RT], as_[RT];
#pragma unroll
        for (int r = 0; r < RT; ++r) { ac[r] = 0.f; as_[r] = 0.f; }
        unsigned E[8], Ow[8];
#pragma unroll
        for (int j = 0; j < 8; ++j) E[j] = xEl[PS + j];
#pragma unroll
        for (int j = 0; j < 6; ++j) Ow[j] = alignhi(E[j + 1], E[j]);

        for (int i8 = 0; i8 < ni; ++i8) {
#pragma unroll
            for (int u = 0; u < 8; ++u) {
                const uint2 wv = wls[i8 * 8 + u];
                const h2_t wc2 = bch(wv.x), ws2 = bch(wv.y);
#pragma unroll
                for (int j = 0; j < 5; ++j) {
                    const h2_t xe = bch(E[(u + j) & 7]);
                    ac[2 * j]      = fdot2(xe, wc2, ac[2 * j]);
                    as_[2 * j]     = fdot2(xe, ws2, as_[2 * j]);
                    const h2_t xo = bch(Ow[(u + j) & 7]);
                    ac[2 * j + 1]  = fdot2(xo, wc2, ac[2 * j + 1]);
                    as_[2 * j + 1] = fdot2(xo, ws2, as_[2 * j + 1]);
                }
                E[u] = xEl[PS + i8 * 8 + u + 8];
                Ow[(u + 6) & 7] = alignhi(E[(u + 7) & 7], E[(u + 6) & 7]);
            }
        }

        // ---- power + thread-local EMA ----
        float p[RT], up[RT];
        float uu = 0.f;
#pragma unroll
        for (int r = 0; r < RT; ++r) {
            p[r] = fmaf(ac[r], ac[r], as_[r] * as_[r]);
            uu = fmaf(a, uu, sw * p[r]);
            up[r] = uu;
        }
        if (chunk == 0 && it == 0 && tid == 0) p0Lds = p[0];

        // ---- EMA Kogge-Stone scan over threads ----
        float v = uu;
        {
            float tv;
            tv = __shfl_up(v, 1);  if (lane >= 1)  v = fmaf(A1,  tv, v);
            tv = __shfl_up(v, 2);  if (lane >= 2)  v = fmaf(A2,  tv, v);
            tv = __shfl_up(v, 4);  if (lane >= 4)  v = fmaf(A4,  tv, v);
            tv = __shfl_up(v, 8);  if (lane >= 8)  v = fmaf(A8,  tv, v);
            tv = __shfl_up(v, 16); if (lane >= 16) v = fmaf(A16, tv, v);
            tv = __shfl_up(v, 32); if (lane >= 32) v = fmaf(A32, tv, v);
        }
        if (lane == 63) waveV[wave] = v;
        __syncthreads();
        if (tid == 0) {
            float c = (chunk == 0 && it == 0) ? p0Lds : carryLds;
#pragma unroll
            for (int w = 0; w < NWAVES; ++w) { cwArr[w] = c; c = fmaf(A64, c, waveV[w]); }
            carryLds = c;
        }
        __syncthreads();
        float cin;
        {
            const float cw = cwArr[wave];
            float ve = __shfl_up(v, 1);
            if (lane == 0) ve = 0.f;
            cin = fmaf(Al, cw, ve);
        }

        // ---- PCEN + f16 ring writes ----
        float apr = a;
#pragma unroll
        for (int j = 0; j < 5; ++j) {
            const float e0 = fmaf(apr, cin, up[2 * j]);     apr *= a;
            const float e1 = fmaf(apr, cin, up[2 * j + 1]); apr *= a;
            const float q0 = fmaf(p[2 * j],     exp2f(-alpha * log2f(EPS_PCENF + e0)), dlt);
            const float q1 = fmaf(p[2 * j + 1], exp2f(-alpha * log2f(EPS_PCENF + e1)), dlt);
            const float c0 = exp2f(inv_r * log2f(q0)) - dpow;
            const float c1 = exp2f(inv_r * log2f(q1)) - dpow;
            ringl[HALOP + P0 + j] = pk2(c0, c1);
        }
        __syncthreads();

        // ---- pooling via dot2: 20 outputs x 16 lanes ----
        if (it >= 0) {
            const int o = tid >> 4, l = tid & 15;
            float part = 0.f;
#pragma unroll
            for (int t = 0; t < 13; ++t) {
                const int kpp = l + 16 * t;   // 0..207, pkpl zero-padded
                part = fdot2(bch(ringl[o * 80 + kpp]), bch(pkpl[kpp]), part);
            }
            part += __shfl_xor(part, 1, 16);
            part += __shfl_xor(part, 2, 16);
            part += __shfl_xor(part, 4, 16);
            part += __shfl_xor(part, 8, 16);
            if (l == 0) pooled[it * NPT + o] += part;
        }
    }
    __syncthreads();

    const float bias = bias_g[f];
    for (int i = tid; i < NPOOL_BLK; i += THREADS)
        out[(size_t)bf * 1000 + (size_t)(tile0 * NPT) + i] = pooled[i] + bias;
}

// ---------- instance norm over 1000 frames, in place ----------
__global__ __launch_bounds__(256) void leaf_norm(float* __restrict__ out)
{
    const int bf = blockIdx.x;
    float* p = out + (size_t)bf * 1000;
    __shared__ float buf[1000];
    __shared__ float red[4];
    const int tid = threadIdx.x;
    const int lane = tid & 63, wave = tid >> 6;

    float sum = 0.0f;
    for (int i = tid; i < 1000; i += 256) { float v = p[i]; buf[i] = v; sum += v; }
    for (int m = 1; m < 64; m <<= 1) sum += __shfl_xor(sum, m);
    if (lane == 0) red[wave] = sum;
    __syncthreads();
    const float mean = (red[0] + red[1] + red[2] + red[3]) * 0.001f;

    float vs = 0.0f;
    for (int i = tid; i < 1000; i += 256) { float d = buf[i] - mean; vs += d * d; }
    for (int m = 1; m < 64; m <<= 1) vs += __shfl_xor(vs, m);
    __syncthreads();
    if (lane == 0) red[wave] = vs;
    __syncthreads();
    const float var   = (red[0] + red[1] + red[2] + red[3]) * 0.001f;
    const float scale = rsqrtf(var + EPS_INF);
    for (int i = tid; i < 1000; i += 256) p[i] = (buf[i] - mean) * scale;
}

extern "C" void kernel_launch(void* const* d_in, const int* in_sizes, int n_in,
                              void* d_out, int out_size, void* d_ws, size_t ws_size,
                              hipStream_t stream)
{
    const float* x     = (const float*)d_in[0];
    const float* eta   = (const float*)d_in[1];
    const float* sigma = (const float*)d_in[2];
    const float* bw    = (const float*)d_in[3];
    const float* bias  = (const float*)d_in[4];
    const float* emaw  = (const float*)d_in[5];
    const float* alpha = (const float*)d_in[6];
    const float* delta = (const float*)d_in[7];
    const float* root  = (const float*)d_in[8];
    float* outp = (float*)d_out;

    uint2*    wtab  = (uint2*)d_ws;                                   // 40*224*8 B
    unsigned* pktab = (unsigned*)((char*)d_ws + (size_t)F_FILT * KPW * sizeof(uint2));

    hipLaunchKernelGGL(leaf_weights, dim3(F_FILT), dim3(256), 0, stream,
                       eta, sigma, bw, wtab, pktab);
    hipLaunchKernelGGL(leaf_main, dim3(B_BATCH * F_FILT * CHUNKS), dim3(THREADS), 0, stream,
                       x, sigma, bias, emaw, alpha, delta, root, wtab, pktab, outp);
    hipLaunchKernelGGL(leaf_norm, dim3(B_BATCH * F_FILT), dim3(256), 0, stream, outp);
}